// Round 5
// baseline (6132.125 us; speedup 1.0000x reference)
//
#include <hip/hip_runtime.h>

#define HID 100
#define TT  1024
#define BPW 4     // batches per workgroup (4*64 = 256 exactly)
#define WPL 64    // workgroups per LSTM
#define NTHR 512

typedef float f32x4 __attribute__((ext_vector_type(4)));

__device__ __forceinline__ float sigf(float x) { return 1.f / (1.f + __expf(-x)); }
__device__ __forceinline__ float tanhf_fast(float x) { return 2.f / (1.f + __expf(-2.f * x)) - 1.f; }
__device__ __forceinline__ float rlane(float v, int l) {
    return __uint_as_float(__builtin_amdgcn_readlane(__float_as_uint(v), l));
}

// R3 lesson (counters): 8 waves x 100 uniform ds_read_b128/step = 6400 clk of
// LDS return-bus time per CU-step == measured 6440 cyc/step. LDS broadcast is
// the wall, NOT weight residency. This version replaces the LDS h-broadcast
// with register-file broadcast: h gathered once per step into lane-distributed
// VGPRs (8 conflict-free ds_read_b32), then v_readlane -> SGPR feeds
// v_fmac_f32 v,s,v directly (1 SGPR operand legal). LDS/step/CU: 800KB -> 16KB.
__global__ __launch_bounds__(NTHR, 2) void lstm3_kernel(
    const float* __restrict__ x1, const float* __restrict__ x2, const float* __restrict__ x3,
    const float* __restrict__ Wih1, const float* __restrict__ Whh1, const float* __restrict__ bi1, const float* __restrict__ bh1,
    const float* __restrict__ Wih2, const float* __restrict__ Whh2, const float* __restrict__ bi2, const float* __restrict__ bh2,
    const float* __restrict__ Wih3, const float* __restrict__ Whh3, const float* __restrict__ bi3, const float* __restrict__ bh3,
    float* __restrict__ hws)
{
    const int wg    = blockIdx.x;
    const int L     = wg / WPL;
    const int bbase = (wg % WPL) * BPW;
    const int tid   = threadIdx.x;

    const float* x   = (L == 0) ? x1   : (L == 1) ? x2   : x3;
    const float* Wih = (L == 0) ? Wih1 : (L == 1) ? Wih2 : Wih3;
    const float* Whh = (L == 0) ? Whh1 : (L == 1) ? Whh2 : Whh3;
    const float* bi  = (L == 0) ? bi1  : (L == 1) ? bi2  : bi3;
    const float* bh  = (L == 0) ? bh1  : (L == 1) ? bh2  : bh3;

    __shared__ __align__(16) float x_lds[BPW][TT][4];   // 64 KiB
    __shared__ __align__(16) float h_lds[2][BPW][HID];  // double-buffered h
    __shared__ __align__(16) float g_lds[BPW][4][HID];  // gates, slot-major

    for (int i = tid; i < BPW * TT; i += NTHR) {
        const int b = i / TT, t = i % TT;
        ((f32x4*)x_lds)[i] = *(const f32x4*)(x + ((size_t)(bbase + b) * TT + t) * 4);
    }
    for (int i = tid; i < BPW * HID; i += NTHR) ((float*)h_lds[0])[i] = 0.f;

    const int  wave = tid >> 6, lane = tid & 63;
    const bool gth  = lane < 50;
    const int  row  = wave * 50 + lane;          // valid if gth
    const int  rowc = wave * 50 + min(lane, 49);
    const int  slot = row / 100;                 // gate slot / update batch
    const int  cell = row % 100;

    // W_hh row: 25 quads in registers
    const f32x4* wp = (const f32x4*)(Whh + (size_t)rowc * HID);
    f32x4 W0  = wp[0],  W1  = wp[1],  W2  = wp[2],  W3  = wp[3],  W4  = wp[4];
    f32x4 W5  = wp[5],  W6  = wp[6],  W7  = wp[7],  W8  = wp[8],  W9  = wp[9];
    f32x4 W10 = wp[10], W11 = wp[11], W12 = wp[12], W13 = wp[13], W14 = wp[14];
    f32x4 W15 = wp[15], W16 = wp[16], W17 = wp[17], W18 = wp[18], W19 = wp[19];
    f32x4 W20 = wp[20], W21 = wp[21], W22 = wp[22], W23 = wp[23], W24 = wp[24];

    f32x4 wi   = *(const f32x4*)(Wih + (size_t)rowc * 4);
    float bias = bi[rowc] + bh[rowc];

    asm volatile("" : "+v"(W0),  "+v"(W1),  "+v"(W2),  "+v"(W3),  "+v"(W4));
    asm volatile("" : "+v"(W5),  "+v"(W6),  "+v"(W7),  "+v"(W8),  "+v"(W9));
    asm volatile("" : "+v"(W10), "+v"(W11), "+v"(W12), "+v"(W13), "+v"(W14));
    asm volatile("" : "+v"(W15), "+v"(W16), "+v"(W17), "+v"(W18), "+v"(W19));
    asm volatile("" : "+v"(W20), "+v"(W21), "+v"(W22), "+v"(W23), "+v"(W24));

    float cc = 0.f, hh = 0.f;   // state of update job (batch=slot, cell)

    const int gidx1 = min(64 + lane, HID - 1);   // clamped index for hr[.][1]

    __syncthreads();

    // GQ: one weight quad (k = base..base+3) x 4 batches.
    // s* come from v_readlane (SGPR); fmac uses SGPR operand directly.
#define GQ(WV, IDX, LB) do {                                                          \
        { const float s0 = rlane(hr##IDX##_0, (LB)+0), s1 = rlane(hr##IDX##_1, (LB)+0), \
                      s2 = rlane(hr##IDX##_2, (LB)+0), s3 = rlane(hr##IDX##_3, (LB)+0); \
          a0 += s0 * WV.x; a1 += s1 * WV.x; a2 += s2 * WV.x; a3 += s3 * WV.x; }        \
        { const float s0 = rlane(hr##IDX##_0, (LB)+1), s1 = rlane(hr##IDX##_1, (LB)+1), \
                      s2 = rlane(hr##IDX##_2, (LB)+1), s3 = rlane(hr##IDX##_3, (LB)+1); \
          a0 += s0 * WV.y; a1 += s1 * WV.y; a2 += s2 * WV.y; a3 += s3 * WV.y; }        \
        { const float s0 = rlane(hr##IDX##_0, (LB)+2), s1 = rlane(hr##IDX##_1, (LB)+2), \
                      s2 = rlane(hr##IDX##_2, (LB)+2), s3 = rlane(hr##IDX##_3, (LB)+2); \
          a0 += s0 * WV.z; a1 += s1 * WV.z; a2 += s2 * WV.z; a3 += s3 * WV.z; }        \
        { const float s0 = rlane(hr##IDX##_0, (LB)+3), s1 = rlane(hr##IDX##_1, (LB)+3), \
                      s2 = rlane(hr##IDX##_2, (LB)+3), s3 = rlane(hr##IDX##_3, (LB)+3); \
          a0 += s0 * WV.w; a1 += s1 * WV.w; a2 += s2 * WV.w; a3 += s3 * WV.w; }        \
    } while (0)

#pragma unroll 1
    for (int st = 0; st < TT; ++st) {
        const int cur = st & 1;

        // gather h into lane-distributed regs: lane l holds h[b][l], h[b][64+l]
        const float hr0_0 = h_lds[cur][0][lane], hr1_0 = h_lds[cur][0][gidx1];
        const float hr0_1 = h_lds[cur][1][lane], hr1_1 = h_lds[cur][1][gidx1];
        const float hr0_2 = h_lds[cur][2][lane], hr1_2 = h_lds[cur][2][gidx1];
        const float hr0_3 = h_lds[cur][3][lane], hr1_3 = h_lds[cur][3][gidx1];

        const f32x4 xb0 = *(const f32x4*)&x_lds[0][st][0];
        const f32x4 xb1 = *(const f32x4*)&x_lds[1][st][0];
        const f32x4 xb2 = *(const f32x4*)&x_lds[2][st][0];
        const f32x4 xb3 = *(const f32x4*)&x_lds[3][st][0];
        float a0 = bias + wi.x * xb0.x + wi.y * xb0.y + wi.z * xb0.z + wi.w * xb0.w;
        float a1 = bias + wi.x * xb1.x + wi.y * xb1.y + wi.z * xb1.z + wi.w * xb1.w;
        float a2 = bias + wi.x * xb2.x + wi.y * xb2.y + wi.z * xb2.z + wi.w * xb2.w;
        float a3 = bias + wi.x * xb3.x + wi.y * xb3.y + wi.z * xb3.z + wi.w * xb3.w;

        // k = 0..63 from hr0_*, k = 64..99 from hr1_* (lanes 0..35)
        GQ(W0,  0, 0);  GQ(W1,  0, 4);  GQ(W2,  0, 8);  GQ(W3,  0, 12);
        GQ(W4,  0, 16); GQ(W5,  0, 20); GQ(W6,  0, 24); GQ(W7,  0, 28);
        GQ(W8,  0, 32); GQ(W9,  0, 36); GQ(W10, 0, 40); GQ(W11, 0, 44);
        GQ(W12, 0, 48); GQ(W13, 0, 52); GQ(W14, 0, 56); GQ(W15, 0, 60);
        GQ(W16, 1, 0);  GQ(W17, 1, 4);  GQ(W18, 1, 8);  GQ(W19, 1, 12);
        GQ(W20, 1, 16); GQ(W21, 1, 20); GQ(W22, 1, 24); GQ(W23, 1, 28);
        GQ(W24, 1, 32);

        if (gth) {
            g_lds[0][slot][cell] = a0;
            g_lds[1][slot][cell] = a1;
            g_lds[2][slot][cell] = a2;
            g_lds[3][slot][cell] = a3;
        }
        __syncthreads();

        if (gth) {
            const float gi = g_lds[slot][0][cell];
            const float gf = g_lds[slot][1][cell];
            const float gg = g_lds[slot][2][cell];
            const float go = g_lds[slot][3][cell];
            cc = sigf(gf) * cc + sigf(gi) * tanhf_fast(gg);
            hh = sigf(go) * tanhf_fast(cc);
            h_lds[cur ^ 1][slot][cell] = hh;
        }
        __syncthreads();
    }
#undef GQ

    if (gth) hws[(size_t)(bbase + slot) * 300 + L * HID + cell] = hh;
}

// out[b][o] = relu(fc_b[o] + sum_j h[b][j] * fc_W[o][j]),  j < 300, o < 12
__global__ __launch_bounds__(64, 1) void fc_kernel(
    const float* __restrict__ hws, const float* __restrict__ fcW,
    const float* __restrict__ fcb, float* __restrict__ out)
{
    const int b = blockIdx.x, lane = threadIdx.x;
    float hv[5];
#pragma unroll
    for (int c = 0; c < 5; c++) {
        const int j = lane + 64 * c;
        hv[c] = (j < 300) ? hws[b * 300 + j] : 0.f;
    }
#pragma unroll
    for (int o = 0; o < 12; o++) {
        float a = 0.f;
#pragma unroll
        for (int c = 0; c < 5; c++) {
            const int j = lane + 64 * c;
            const float wv = (j < 300) ? fcW[o * 300 + j] : 0.f;
            a += hv[c] * wv;
        }
#pragma unroll
        for (int off = 32; off > 0; off >>= 1) a += __shfl_xor(a, off, 64);
        if (lane == 0) out[b * 12 + o] = fmaxf(a + fcb[o], 0.f);
    }
}

extern "C" void kernel_launch(void* const* d_in, const int* in_sizes, int n_in,
                              void* d_out, int out_size, void* d_ws, size_t ws_size,
                              hipStream_t stream)
{
    const float* x1   = (const float*)d_in[0];
    const float* x2   = (const float*)d_in[1];
    const float* x3   = (const float*)d_in[2];
    const float* Wih1 = (const float*)d_in[3];
    const float* Whh1 = (const float*)d_in[4];
    const float* bi1  = (const float*)d_in[5];
    const float* bh1  = (const float*)d_in[6];
    const float* Wih2 = (const float*)d_in[7];
    const float* Whh2 = (const float*)d_in[8];
    const float* bi2  = (const float*)d_in[9];
    const float* bh2  = (const float*)d_in[10];
    const float* Wih3 = (const float*)d_in[11];
    const float* Whh3 = (const float*)d_in[12];
    const float* bi3  = (const float*)d_in[13];
    const float* bh3  = (const float*)d_in[14];
    const float* fcW  = (const float*)d_in[15];
    const float* fcb  = (const float*)d_in[16];

    float* hws = (float*)d_ws;  // 256*300 floats = 300 KiB

    lstm3_kernel<<<3 * WPL, NTHR, 0, stream>>>(x1, x2, x3,
                                               Wih1, Whh1, bi1, bh1,
                                               Wih2, Whh2, bi2, bh2,
                                               Wih3, Whh3, bi3, bh3, hws);
    fc_kernel<<<256, 64, 0, stream>>>(hws, fcW, fcb, (float*)d_out);
}